// Round 1
// baseline (196.743 us; speedup 1.0000x reference)
//
#include <hip/hip_runtime.h>
#include <math.h>

// NonLocalBlock: B=4, C=256, Cb=128, H=W=64, N=HW=4096.
// Round 11: k3 barrier-window shrink. r10 counters: MfmaUtil 24%, VALUBusy 25%,
// ~50% idle -> barrier/dependency stall. Delta vs r10 (proven r6 shape kept):
//   (a) Pl double-buffered (LDS 27.6->37.4KB, still 4 blocks/CU) so the
//       exp+f2bf+P-write moves BEFORE barrier 1 -> B1..B2 window is only the
//       4 Lphi ds_write_b128.
//   (b) T5 s_setprio(1) around S and PV MFMA clusters (and k2 MFMA bursts).
constexpr int CI = 256;
constexpr int CB = 128;
constexpr int HWD = 4096;
constexpr int NBATCH = 4;
constexpr int NN_ = 4096;
constexpr size_t U1 = (size_t)NBATCH * NN_ * CB;            // 2,097,152
constexpr size_t U_THETA = 0;
constexpr size_t U_PHIT  = U1;
constexpr size_t U_G     = 2 * U1;
constexpr size_t U_GT    = 3 * U1;
constexpr size_t U_Y     = 4 * U1;                          // 4 m-quarter partials
constexpr size_t U_XT    = 4 * U1;                          // alias (xT dead before k3)
constexpr size_t U_WCAT  = 8 * U1;
constexpr size_t U_WW    = 8 * U1 + 98304;
constexpr size_t F_D     = (8 * U1 + 131072) / 2;

typedef short v8s __attribute__((ext_vector_type(8)));
typedef unsigned short u8s __attribute__((ext_vector_type(8)));
typedef float v4f __attribute__((ext_vector_type(4)));
typedef float v16f __attribute__((ext_vector_type(16)));
#define MFMA16(a, b, c) __builtin_amdgcn_mfma_f32_16x16x32_bf16(a, b, c, 0, 0, 0)
#define MFMA32(a, b, c) __builtin_amdgcn_mfma_f32_32x32x16_bf16(a, b, c, 0, 0, 0)

__device__ __forceinline__ unsigned short f2bf(float f) {
    union { float f; unsigned u; } v; v.f = f;
    unsigned r = v.u + 0x7fff + ((v.u >> 16) & 1);
    return (unsigned short)(r >> 16);
}
__device__ __forceinline__ float bf2f(unsigned short s) {
    union { unsigned u; float f; } v; v.u = (unsigned)s << 16;
    return v.f;
}

// ---------------- k0: xT transpose + (fused) weight bf16 convert ------------
__global__ __launch_bounds__(256) void k0_xpose(
    const float* __restrict__ x, unsigned short* __restrict__ xT,
    const float* __restrict__ tw, const float* __restrict__ pw,
    const float* __restrict__ gw, const float* __restrict__ Ww,
    unsigned short* __restrict__ wcat, unsigned short* __restrict__ wwB)
{
    __shared__ unsigned short T[64 * 72];
    const int t = threadIdx.x;
    if (blockIdx.y == 4) {
        int wb = blockIdx.x + 64 * blockIdx.z;
        if (t < 128) {
            int e = (wb * 128 + t) * 4;
            const float* src; unsigned short* dst;
            if (e < 32768)       { src = tw + e;           dst = wcat + e; }
            else if (e < 65536)  { src = pw + (e - 32768); dst = wcat + e; }
            else if (e < 98304)  { src = gw + (e - 65536); dst = wcat + e; }
            else                 { src = Ww + (e - 98304); dst = wwB + (e - 98304); }
            float4 f = *(const float4*)src;
            ushort4 u;
            u.x = f2bf(f.x); u.y = f2bf(f.y); u.z = f2bf(f.z); u.w = f2bf(f.w);
            *(ushort4*)dst = u;
        }
        return;
    }
    const int hw0 = blockIdx.x * 64, c0 = blockIdx.y * 64, b = blockIdx.z;
    const float* xb = x + (size_t)b * CI * HWD;
    const int rr = t >> 4, cc = t & 15;
    #pragma unroll
    for (int pass = 0; pass < 4; pass++) {
        float4 f = *(const float4*)&xb[(size_t)(c0 + pass * 16 + rr) * HWD + hw0 + cc * 4];
        T[(cc * 4 + 0) * 72 + pass * 16 + rr] = f2bf(f.x);
        T[(cc * 4 + 1) * 72 + pass * 16 + rr] = f2bf(f.y);
        T[(cc * 4 + 2) * 72 + pass * 16 + rr] = f2bf(f.z);
        T[(cc * 4 + 3) * 72 + pass * 16 + rr] = f2bf(f.w);
    }
    __syncthreads();
    const int row = t >> 2, cs = (t & 3) * 16;
    unsigned short* dst = xT + (size_t)b * NN_ * CI;
    #pragma unroll
    for (int h = 0; h < 2; h++)
        *(u8s*)&dst[(size_t)(hw0 + row) * CI + c0 + cs + h * 8] =
            *(const u8s*)&T[row * 72 + cs + h * 8];
}

// ---------------- k1: tpg = Wcat @ x, 32x32x16, xT tile staged in LDS -------
__global__ __launch_bounds__(256, 4) void k1_mfma(
    const unsigned short* __restrict__ xT, const unsigned short* __restrict__ wcat,
    const float* __restrict__ tb, const float* __restrict__ pb,
    const float* __restrict__ gb,
    unsigned short* __restrict__ thetaB, unsigned short* __restrict__ phiTB,
    unsigned short* __restrict__ gB)
{
    __shared__ unsigned short LdsX[64 * 268];
    unsigned short* T = LdsX;
    const int t = threadIdx.x;
    const int lane = t & 63, w = t >> 6;
    const int l31 = lane & 31, lh = lane >> 5;
    const int qj = w >> 1, qh = w & 1;
    const int hw0 = blockIdx.x * 64, j0 = blockIdx.y * 64, b = blockIdx.z;
    const int matId = j0 >> 7, jl0 = j0 & 127;
    const float* bvec = (matId == 0) ? tb : (matId == 1) ? pb : gb;
    const unsigned short* xb = xT + (size_t)b * NN_ * CI;

    {
        const int row = t >> 2, seg = t & 3;
        #pragma unroll
        for (int c8 = 0; c8 < 8; c8++)
            *(u8s*)&LdsX[row * 268 + seg * 64 + c8 * 8] =
                *(const u8s*)&xb[(size_t)(hw0 + row) * CI + seg * 64 + c8 * 8];
    }
    __syncthreads();

    v16f s = {};
    #pragma unroll
    for (int kt = 0; kt < 16; kt++) {
        v8s a = *(const v8s*)&wcat[(size_t)(j0 + qj * 32 + l31) * CI + kt * 16 + lh * 8];
        v8s bx = *(const v8s*)&LdsX[(qh * 32 + l31) * 268 + kt * 16 + lh * 8];
        s = MFMA32(a, bx, s);
    }

    if (matId != 1) {
        unsigned short* dst = ((matId == 0) ? thetaB : gB) + (size_t)b * CB * HWD;
        #pragma unroll
        for (int reg = 0; reg < 16; reg++) {
            int row = (reg & 3) + 8 * (reg >> 2) + 4 * lh;
            int cb = jl0 + qj * 32 + row;
            dst[(size_t)cb * HWD + hw0 + qh * 32 + l31] = f2bf(s[reg] + bvec[cb]);
        }
    } else {
        __syncthreads();
        #pragma unroll
        for (int reg = 0; reg < 16; reg++) {
            int row = (reg & 3) + 8 * (reg >> 2) + 4 * lh;
            T[(qh * 32 + l31) * 76 + qj * 32 + row] =
                f2bf(s[reg] + bvec[jl0 + qj * 32 + row]);
        }
        __syncthreads();
        unsigned short* dst = phiTB + (size_t)b * NN_ * CB;
        const int row = t >> 2, cs = (t & 3) * 16;
        #pragma unroll
        for (int h = 0; h < 2; h++)
            *(u8s*)&dst[(size_t)(hw0 + row) * CB + jl0 + cs + h * 8] =
                *(const u8s*)&T[row * 76 + cs + h * 8];
    }
}

// ---------------- k2: D[m] = sum_n exp(S[n][m]), m-tile 128 -----------------
__global__ __launch_bounds__(256, 2) void k2_colsum(
    const unsigned short* __restrict__ thetaB,
    const unsigned short* __restrict__ phiTB,
    float* __restrict__ Dout)
{
    __shared__ float part[4][128];
    const int t = threadIdx.x;
    const int lane = t & 63, w = t >> 6;
    const int ln = lane & 15, quad = lane >> 4;
    const int m0 = blockIdx.x * 128, q = blockIdx.y, b = blockIdx.z;
    const unsigned short* th = thetaB + (size_t)b * NN_ * CB;
    const unsigned short* ph = phiTB + (size_t)b * NN_ * CB;

    v8s bf[8][4];
    #pragma unroll
    for (int mt = 0; mt < 8; mt++)
        #pragma unroll
        for (int kt = 0; kt < 4; kt++)
            bf[mt][kt] = *(const v8s*)&ph[(size_t)(m0 + mt * 16 + ln) * CB + kt * 32 + quad * 8];

    float dsum[8] = {};
    const int nBeg = q * 1024 + w * 16, nEnd = q * 1024 + 1024;
    v8s af[4], afn[4];
    #pragma unroll
    for (int kt = 0; kt < 4; kt++)
        af[kt] = *(const v8s*)&th[(size_t)(nBeg + ln) * CB + kt * 32 + quad * 8];
    for (int n0 = nBeg; n0 < nEnd; n0 += 64) {
        int nn = (n0 + 64 < nEnd) ? n0 + 64 : nBeg;
        #pragma unroll
        for (int kt = 0; kt < 4; kt++)
            afn[kt] = *(const v8s*)&th[(size_t)(nn + ln) * CB + kt * 32 + quad * 8];
        #pragma unroll
        for (int mt = 0; mt < 8; mt++) {
            v4f s = {};
            __builtin_amdgcn_s_setprio(1);
            #pragma unroll
            for (int kt = 0; kt < 4; kt++)
                s = MFMA16(af[kt], bf[mt][kt], s);
            __builtin_amdgcn_s_setprio(0);
            #pragma unroll
            for (int r = 0; r < 4; r++)
                dsum[mt] += __expf(s[r]);
        }
        #pragma unroll
        for (int kt = 0; kt < 4; kt++) af[kt] = afn[kt];
    }
    #pragma unroll
    for (int mt = 0; mt < 8; mt++) {
        float v = dsum[mt];
        v += __shfl_xor(v, 16);
        v += __shfl_xor(v, 32);
        dsum[mt] = v;
    }
    if (quad == 0) {
        #pragma unroll
        for (int mt = 0; mt < 8; mt++) part[w][mt * 16 + ln] = dsum[mt];
    }
    __syncthreads();
    if (t < 128) {
        float v = part[0][t] + part[1][t] + part[2][t] + part[3][t];
        Dout[((size_t)q * NBATCH + b) * NN_ + m0 + t] = v;
    }
}

// ---------------- k1b: gT[c][m] = F[m*128+c] / D[m], LDS transpose ----------
__global__ __launch_bounds__(256) void k1b_transpose_scale_g(
    const unsigned short* __restrict__ gB, const float* __restrict__ D,
    unsigned short* __restrict__ gTB)
{
    __shared__ unsigned short T[128 * 36];
    const int t = threadIdx.x;
    const int m0 = blockIdx.x * 32;
    const int b  = blockIdx.z;
    const unsigned short* F = gB + (size_t)b * CB * HWD;
    unsigned short* dst = gTB + (size_t)b * CB * HWD;
    const int mrow = t >> 3, cg = t & 7;
    {
        int m = m0 + mrow;
        float d = D[((size_t)0 * NBATCH + b) * NN_ + m]
                + D[((size_t)1 * NBATCH + b) * NN_ + m]
                + D[((size_t)2 * NBATCH + b) * NN_ + m]
                + D[((size_t)3 * NBATCH + b) * NN_ + m];
        float r = 1.0f / d;
        #pragma unroll
        for (int j8 = 0; j8 < 2; j8++) {
            int cbase = cg * 8 + j8 * 64;
            u8s u = *(const u8s*)&F[(size_t)m * CB + cbase];
            #pragma unroll
            for (int e = 0; e < 8; e++)
                T[(cbase + e) * 36 + mrow] = f2bf(bf2f(u[e]) * r);
        }
    }
    __syncthreads();
    const int c = t >> 1, mh = (t & 1) * 16;
    #pragma unroll
    for (int h8 = 0; h8 < 2; h8++)
        *(u8s*)&dst[(size_t)c * HWD + m0 + mh + h8 * 8] =
            *(const u8s*)&T[c * 36 + mh + h8 * 8];
}

// ---------------- k3: y[n][c] = sum_m exp(S[n][m]) * gT[c][m], 32x32x16 -----
// r6-proven geometry: 64n x 128c block, Lphi LDS staging, 2 barriers/iter,
// quadrant S. Round-11 deltas: (a) Pl double-buffered so exp+P-write sits
// BEFORE barrier 1 (B1..B2 window = only 4 Lphi ds_write_b128);
// (b) s_setprio(1) around the S and PV MFMA clusters.
// Race audit for (a): exp-writes(i) -> Pl[i&1]; last readers of that buffer
// were PV(i-2), and barriers B1(i-1)/B2(i-1) (with their lgkmcnt(0) drains)
// separate PV(i-2) reads from exp-writes(i) on every wave pair.
__global__ __launch_bounds__(256, 4) void k3_attn(
    const unsigned short* __restrict__ thetaB,
    const unsigned short* __restrict__ phiTB,
    const unsigned short* __restrict__ gTB,
    unsigned short* __restrict__ Y)
{
    __shared__ unsigned short Lphi[64 * 140];   // [m-local][k], 280B stride
    __shared__ unsigned short Pl[2][64 * 76];   // double-buffered [n-local][m-local]
    const int t = threadIdx.x;
    const int lane = t & 63, w = t >> 6;
    const int l31 = lane & 31, lh = lane >> 5;
    const int qn = w & 1, qm = w >> 1;
    const int rowS = t >> 4, colS = t & 15;
    const int n0 = blockIdx.x * 64, q = blockIdx.y, b = blockIdx.z;
    const unsigned short* th = thetaB + (size_t)b * NN_ * CB;
    const unsigned short* ph = phiTB + (size_t)b * NN_ * CB;
    const unsigned short* gT = gTB + (size_t)b * CB * HWD;

    // persistent theta A-frags: rows n0+qn*32+l31, k = 128 in 8 steps of 16
    v8s ath[8];
    #pragma unroll
    for (int kt = 0; kt < 8; kt++)
        ath[kt] = *(const v8s*)&th[(size_t)(n0 + qn * 32 + l31) * CB + kt * 16 + lh * 8];

    const int mBeg = q * 1024, mEnd = mBeg + 1024;
    #pragma unroll
    for (int pass = 0; pass < 4; pass++)
        *(v8s*)&Lphi[(pass * 16 + rowS) * 140 + colS * 8] =
            *(const v8s*)&ph[(size_t)(mBeg + pass * 16 + rowS) * CB + colS * 8];
    __syncthreads();

    v16f yacc[2] = {};   // nt = 0,1 (n halves); wave's c-strip = w*32
    int pb = 0;
    for (int m0 = mBeg; m0 < mEnd; m0 += 64, pb ^= 1) {
        int mN = (m0 + 64 < mEnd) ? m0 + 64 : mBeg;
        v8s preg[4];
        #pragma unroll
        for (int pass = 0; pass < 4; pass++)
            preg[pass] = *(const v8s*)&ph[(size_t)(mN + pass * 16 + rowS) * CB + colS * 8];
        // gT prefetch for this iter (consumed in PV after the 2nd barrier)
        v8s gfrag[4];
        #pragma unroll
        for (int ks = 0; ks < 4; ks++)
            gfrag[ks] = *(const v8s*)&gT[(size_t)(w * 32 + l31) * HWD + m0 + ks * 16 + lh * 8];
        // S phase: one 32x32 quadrant per wave, phi from LDS
        __builtin_amdgcn_s_setprio(1);
        v16f s = {};
        #pragma unroll
        for (int kt = 0; kt < 8; kt++) {
            v8s bphi = *(const v8s*)&Lphi[(qm * 32 + l31) * 140 + kt * 16 + lh * 8];
            s = MFMA32(ath[kt], bphi, s);
        }
        __builtin_amdgcn_s_setprio(0);
        // exp + P-write to the ping-pong buffer BEFORE B1: overlaps other
        // waves' S MFMA instead of sitting in the inter-barrier window.
        #pragma unroll
        for (int reg = 0; reg < 16; reg++) {
            int row = qn * 32 + (reg & 3) + 8 * (reg >> 2) + 4 * lh;   // n-local
            Pl[pb][row * 76 + qm * 32 + l31] = f2bf(__expf(s[reg]));
        }
        __syncthreads();   // all waves: Lphi S-reads done + Pl[pb] writes drained
        #pragma unroll
        for (int pass = 0; pass < 4; pass++)
            *(v8s*)&Lphi[(pass * 16 + rowS) * 140 + colS * 8] = preg[pass];
        __syncthreads();   // Lphi(i+1) visible to all waves
        // PV phase: wave's 32-c strip (w*32), both n 32-halves
        __builtin_amdgcn_s_setprio(1);
        #pragma unroll
        for (int ks = 0; ks < 4; ks++)
            #pragma unroll
            for (int nt = 0; nt < 2; nt++) {
                v8s ap = *(const v8s*)&Pl[pb][(nt * 32 + l31) * 76 + ks * 16 + lh * 8];
                yacc[nt] = MFMA32(ap, gfrag[ks], yacc[nt]);
            }
        __builtin_amdgcn_s_setprio(0);
    }
    unsigned short* yp = Y + ((size_t)q * NBATCH + b) * CB * HWD;
    #pragma unroll
    for (int nt = 0; nt < 2; nt++)
        #pragma unroll
        for (int reg = 0; reg < 16; reg++) {
            int row = (reg & 3) + 8 * (reg >> 2) + 4 * lh;
            yp[(size_t)(n0 + nt * 32 + row) * CB + w * 32 + l31] = f2bf(yacc[nt][reg]);
        }
}

// ---------------- k4: out = Ww @ (sum Y partials) + Wb + x ------------------
__global__ __launch_bounds__(256, 2) void k4_mfma(
    const float* __restrict__ x, const unsigned short* __restrict__ wwB,
    const float* __restrict__ Wb, const unsigned short* __restrict__ Ybuf,
    float* __restrict__ out)
{
    __shared__ unsigned short Yt[64 * 136];
    const int t = threadIdx.x;
    const int lane = t & 63, w = t >> 6;
    const int ln = lane & 15, quad = lane >> 4;
    const int hw0 = blockIdx.x * 64, o0 = blockIdx.y * 128, b = blockIdx.z;

    const int cb = t >> 1, seg = (t & 1) * 32;
    #pragma unroll
    for (int g8 = 0; g8 < 4; g8++) {
        float sum[8] = {};
        #pragma unroll
        for (int q = 0; q < 4; q++) {
            u8s u = *(const u8s*)&Ybuf[((size_t)q * NBATCH + b) * CB * HWD +
                                       (size_t)cb * HWD + hw0 + seg + g8 * 8];
            #pragma unroll
            for (int j = 0; j < 8; j++) sum[j] += bf2f(u[j]);
        }
        #pragma unroll
        for (int j = 0; j < 8; j++)
            Yt[(seg + g8 * 8 + j) * 136 + cb] = f2bf(sum[j]);
    }
    __syncthreads();

    v8s aw[2][4];
    #pragma unroll
    for (int os = 0; os < 2; os++)
        #pragma unroll
        for (int kt = 0; kt < 4; kt++)
            aw[os][kt] = *(const v8s*)&wwB[(size_t)(o0 + w * 32 + os * 16 + ln) * CB + kt * 32 + quad * 8];

    v4f s[2][4] = {};
    #pragma unroll
    for (int kt = 0; kt < 4; kt++) {
        v8s by[4];
        #pragma unroll
        for (int mt = 0; mt < 4; mt++)
            by[mt] = *(const v8s*)&Yt[(mt * 16 + ln) * 136 + kt * 32 + quad * 8];
        #pragma unroll
        for (int os = 0; os < 2; os++)
            #pragma unroll
            for (int mt = 0; mt < 4; mt++)
                s[os][mt] = MFMA16(aw[os][kt], by[mt], s[os][mt]);
    }
    #pragma unroll
    for (int os = 0; os < 2; os++)
        #pragma unroll
        for (int mt = 0; mt < 4; mt++)
            #pragma unroll
            for (int r = 0; r < 4; r++) {
                int o = o0 + w * 32 + os * 16 + quad * 4 + r;
                size_t idx = (size_t)b * CI * HWD + (size_t)o * HWD + hw0 + mt * 16 + ln;
                out[idx] = s[os][mt][r] + Wb[o] + x[idx];
            }
}

extern "C" void kernel_launch(void* const* d_in, const int* in_sizes, int n_in,
                              void* d_out, int out_size, void* d_ws, size_t ws_size,
                              hipStream_t stream)
{
    const float* x  = (const float*)d_in[0];
    const float* tw = (const float*)d_in[1];
    const float* tb = (const float*)d_in[2];
    const float* pw = (const float*)d_in[3];
    const float* pb = (const float*)d_in[4];
    const float* gw = (const float*)d_in[5];
    const float* gb = (const float*)d_in[6];
    const float* Ww = (const float*)d_in[7];
    const float* Wb = (const float*)d_in[8];
    unsigned short* wsu = (unsigned short*)d_ws;
    float* wsf = (float*)d_ws;
    unsigned short* thetaB = wsu + U_THETA;
    unsigned short* phiTB  = wsu + U_PHIT;
    unsigned short* gB     = wsu + U_G;
    unsigned short* gTB    = wsu + U_GT;
    unsigned short* Ybuf   = wsu + U_Y;
    unsigned short* xTB    = wsu + U_XT;
    unsigned short* wcatB  = wsu + U_WCAT;
    unsigned short* wwB    = wsu + U_WW;
    float* Dbuf = wsf + F_D;
    float* out = (float*)d_out;
    dim3 blk(256, 1, 1);
    hipLaunchKernelGGL(k0_xpose, dim3(64, 5, NBATCH), blk, 0, stream,
                       x, xTB, tw, pw, gw, Ww, wcatB, wwB);
    hipLaunchKernelGGL(k1_mfma, dim3(64, 6, NBATCH), blk, 0, stream,
                       xTB, wcatB, tb, pb, gb, thetaB, phiTB, gB);
    hipLaunchKernelGGL(k2_colsum, dim3(32, 4, NBATCH), blk, 0, stream,
                       thetaB, phiTB, Dbuf);
    hipLaunchKernelGGL(k1b_transpose_scale_g, dim3(128, 1, NBATCH), blk, 0, stream,
                       gB, Dbuf, gTB);
    hipLaunchKernelGGL(k3_attn, dim3(64, 4, NBATCH), blk, 0, stream,
                       thetaB, phiTB, gTB, Ybuf);
    hipLaunchKernelGGL(k4_mfma, dim3(64, 2, NBATCH), blk, 0, stream,
                       x, wwB, Wb, Ybuf, out);
}

// Round 4
// 196.284 us; speedup vs baseline: 1.0023x; 1.0023x over previous
//
#include <hip/hip_runtime.h>
#include <math.h>

// NonLocalBlock: B=4, C=256, Cb=128, H=W=64, N=HW=4096.
// Round 14: single-barrier k3 via full double-buffering, __syncthreads only.
// r12/r13 (raw s_barrier, no vmcnt drain) failed the container twice -> that
// construct is abandoned. Same theory tested safely: halve barrier/drain
// events (2 -> 1 per m-iter) with Lphi+Pl both double-buffered, and schedule
// prefetches so they are >=500cy old at each drain (preg issued POST-barrier,
// gfrag issued at iter top, consumed post-barrier).
// LDS 51.2KB -> 3 blocks/CU (was 4). Hazards: every cross-wave pair
// (Lphi write vs S-reads, Pl write vs PV-reads) separated by one barrier.
constexpr int CI = 256;
constexpr int CB = 128;
constexpr int HWD = 4096;
constexpr int NBATCH = 4;
constexpr int NN_ = 4096;
constexpr size_t U1 = (size_t)NBATCH * NN_ * CB;            // 2,097,152
constexpr size_t U_THETA = 0;
constexpr size_t U_PHIT  = U1;
constexpr size_t U_G     = 2 * U1;
constexpr size_t U_GT    = 3 * U1;
constexpr size_t U_Y     = 4 * U1;                          // 4 m-quarter partials
constexpr size_t U_XT    = 4 * U1;                          // alias (xT dead before k3)
constexpr size_t U_WCAT  = 8 * U1;
constexpr size_t U_WW    = 8 * U1 + 98304;
constexpr size_t F_D     = (8 * U1 + 131072) / 2;

typedef short v8s __attribute__((ext_vector_type(8)));
typedef unsigned short u8s __attribute__((ext_vector_type(8)));
typedef float v4f __attribute__((ext_vector_type(4)));
typedef float v16f __attribute__((ext_vector_type(16)));
#define MFMA16(a, b, c) __builtin_amdgcn_mfma_f32_16x16x32_bf16(a, b, c, 0, 0, 0)
#define MFMA32(a, b, c) __builtin_amdgcn_mfma_f32_32x32x16_bf16(a, b, c, 0, 0, 0)

__device__ __forceinline__ unsigned short f2bf(float f) {
    union { float f; unsigned u; } v; v.f = f;
    unsigned r = v.u + 0x7fff + ((v.u >> 16) & 1);
    return (unsigned short)(r >> 16);
}
__device__ __forceinline__ float bf2f(unsigned short s) {
    union { unsigned u; float f; } v; v.u = (unsigned)s << 16;
    return v.f;
}

// ---------------- k0: xT transpose + (fused) weight bf16 convert ------------
__global__ __launch_bounds__(256) void k0_xpose(
    const float* __restrict__ x, unsigned short* __restrict__ xT,
    const float* __restrict__ tw, const float* __restrict__ pw,
    const float* __restrict__ gw, const float* __restrict__ Ww,
    unsigned short* __restrict__ wcat, unsigned short* __restrict__ wwB)
{
    __shared__ unsigned short T[64 * 72];
    const int t = threadIdx.x;
    if (blockIdx.y == 4) {
        int wb = blockIdx.x + 64 * blockIdx.z;
        if (t < 128) {
            int e = (wb * 128 + t) * 4;
            const float* src; unsigned short* dst;
            if (e < 32768)       { src = tw + e;           dst = wcat + e; }
            else if (e < 65536)  { src = pw + (e - 32768); dst = wcat + e; }
            else if (e < 98304)  { src = gw + (e - 65536); dst = wcat + e; }
            else                 { src = Ww + (e - 98304); dst = wwB + (e - 98304); }
            float4 f = *(const float4*)src;
            ushort4 u;
            u.x = f2bf(f.x); u.y = f2bf(f.y); u.z = f2bf(f.z); u.w = f2bf(f.w);
            *(ushort4*)dst = u;
        }
        return;
    }
    const int hw0 = blockIdx.x * 64, c0 = blockIdx.y * 64, b = blockIdx.z;
    const float* xb = x + (size_t)b * CI * HWD;
    const int rr = t >> 4, cc = t & 15;
    #pragma unroll
    for (int pass = 0; pass < 4; pass++) {
        float4 f = *(const float4*)&xb[(size_t)(c0 + pass * 16 + rr) * HWD + hw0 + cc * 4];
        T[(cc * 4 + 0) * 72 + pass * 16 + rr] = f2bf(f.x);
        T[(cc * 4 + 1) * 72 + pass * 16 + rr] = f2bf(f.y);
        T[(cc * 4 + 2) * 72 + pass * 16 + rr] = f2bf(f.z);
        T[(cc * 4 + 3) * 72 + pass * 16 + rr] = f2bf(f.w);
    }
    __syncthreads();
    const int row = t >> 2, cs = (t & 3) * 16;
    unsigned short* dst = xT + (size_t)b * NN_ * CI;
    #pragma unroll
    for (int h = 0; h < 2; h++)
        *(u8s*)&dst[(size_t)(hw0 + row) * CI + c0 + cs + h * 8] =
            *(const u8s*)&T[row * 72 + cs + h * 8];
}

// ---------------- k1: tpg = Wcat @ x, 32x32x16, xT tile staged in LDS -------
__global__ __launch_bounds__(256, 4) void k1_mfma(
    const unsigned short* __restrict__ xT, const unsigned short* __restrict__ wcat,
    const float* __restrict__ tb, const float* __restrict__ pb,
    const float* __restrict__ gb,
    unsigned short* __restrict__ thetaB, unsigned short* __restrict__ phiTB,
    unsigned short* __restrict__ gB)
{
    __shared__ unsigned short LdsX[64 * 268];
    unsigned short* T = LdsX;
    const int t = threadIdx.x;
    const int lane = t & 63, w = t >> 6;
    const int l31 = lane & 31, lh = lane >> 5;
    const int qj = w >> 1, qh = w & 1;
    const int hw0 = blockIdx.x * 64, j0 = blockIdx.y * 64, b = blockIdx.z;
    const int matId = j0 >> 7, jl0 = j0 & 127;
    const float* bvec = (matId == 0) ? tb : (matId == 1) ? pb : gb;
    const unsigned short* xb = xT + (size_t)b * NN_ * CI;

    {
        const int row = t >> 2, seg = t & 3;
        #pragma unroll
        for (int c8 = 0; c8 < 8; c8++)
            *(u8s*)&LdsX[row * 268 + seg * 64 + c8 * 8] =
                *(const u8s*)&xb[(size_t)(hw0 + row) * CI + seg * 64 + c8 * 8];
    }
    __syncthreads();

    v16f s = {};
    #pragma unroll
    for (int kt = 0; kt < 16; kt++) {
        v8s a = *(const v8s*)&wcat[(size_t)(j0 + qj * 32 + l31) * CI + kt * 16 + lh * 8];
        v8s bx = *(const v8s*)&LdsX[(qh * 32 + l31) * 268 + kt * 16 + lh * 8];
        s = MFMA32(a, bx, s);
    }

    if (matId != 1) {
        unsigned short* dst = ((matId == 0) ? thetaB : gB) + (size_t)b * CB * HWD;
        #pragma unroll
        for (int reg = 0; reg < 16; reg++) {
            int row = (reg & 3) + 8 * (reg >> 2) + 4 * lh;
            int cb = jl0 + qj * 32 + row;
            dst[(size_t)cb * HWD + hw0 + qh * 32 + l31] = f2bf(s[reg] + bvec[cb]);
        }
    } else {
        __syncthreads();
        #pragma unroll
        for (int reg = 0; reg < 16; reg++) {
            int row = (reg & 3) + 8 * (reg >> 2) + 4 * lh;
            T[(qh * 32 + l31) * 76 + qj * 32 + row] =
                f2bf(s[reg] + bvec[jl0 + qj * 32 + row]);
        }
        __syncthreads();
        unsigned short* dst = phiTB + (size_t)b * NN_ * CB;
        const int row = t >> 2, cs = (t & 3) * 16;
        #pragma unroll
        for (int h = 0; h < 2; h++)
            *(u8s*)&dst[(size_t)(hw0 + row) * CB + jl0 + cs + h * 8] =
                *(const u8s*)&T[row * 76 + cs + h * 8];
    }
}

// ---------------- k2: D[m] = sum_n exp(S[n][m]), m-tile 128 -----------------
__global__ __launch_bounds__(256, 2) void k2_colsum(
    const unsigned short* __restrict__ thetaB,
    const unsigned short* __restrict__ phiTB,
    float* __restrict__ Dout)
{
    __shared__ float part[4][128];
    const int t = threadIdx.x;
    const int lane = t & 63, w = t >> 6;
    const int ln = lane & 15, quad = lane >> 4;
    const int m0 = blockIdx.x * 128, q = blockIdx.y, b = blockIdx.z;
    const unsigned short* th = thetaB + (size_t)b * NN_ * CB;
    const unsigned short* ph = phiTB + (size_t)b * NN_ * CB;

    v8s bf[8][4];
    #pragma unroll
    for (int mt = 0; mt < 8; mt++)
        #pragma unroll
        for (int kt = 0; kt < 4; kt++)
            bf[mt][kt] = *(const v8s*)&ph[(size_t)(m0 + mt * 16 + ln) * CB + kt * 32 + quad * 8];

    float dsum[8] = {};
    const int nBeg = q * 1024 + w * 16, nEnd = q * 1024 + 1024;
    v8s af[4], afn[4];
    #pragma unroll
    for (int kt = 0; kt < 4; kt++)
        af[kt] = *(const v8s*)&th[(size_t)(nBeg + ln) * CB + kt * 32 + quad * 8];
    for (int n0 = nBeg; n0 < nEnd; n0 += 64) {
        int nn = (n0 + 64 < nEnd) ? n0 + 64 : nBeg;
        #pragma unroll
        for (int kt = 0; kt < 4; kt++)
            afn[kt] = *(const v8s*)&th[(size_t)(nn + ln) * CB + kt * 32 + quad * 8];
        #pragma unroll
        for (int mt = 0; mt < 8; mt++) {
            v4f s = {};
            #pragma unroll
            for (int kt = 0; kt < 4; kt++)
                s = MFMA16(af[kt], bf[mt][kt], s);
            #pragma unroll
            for (int r = 0; r < 4; r++)
                dsum[mt] += __expf(s[r]);
        }
        #pragma unroll
        for (int kt = 0; kt < 4; kt++) af[kt] = afn[kt];
    }
    #pragma unroll
    for (int mt = 0; mt < 8; mt++) {
        float v = dsum[mt];
        v += __shfl_xor(v, 16);
        v += __shfl_xor(v, 32);
        dsum[mt] = v;
    }
    if (quad == 0) {
        #pragma unroll
        for (int mt = 0; mt < 8; mt++) part[w][mt * 16 + ln] = dsum[mt];
    }
    __syncthreads();
    if (t < 128) {
        float v = part[0][t] + part[1][t] + part[2][t] + part[3][t];
        Dout[((size_t)q * NBATCH + b) * NN_ + m0 + t] = v;
    }
}

// ---------------- k1b: gT[c][m] = F[m*128+c] / D[m], LDS transpose ----------
__global__ __launch_bounds__(256) void k1b_transpose_scale_g(
    const unsigned short* __restrict__ gB, const float* __restrict__ D,
    unsigned short* __restrict__ gTB)
{
    __shared__ unsigned short T[128 * 36];
    const int t = threadIdx.x;
    const int m0 = blockIdx.x * 32;
    const int b  = blockIdx.z;
    const unsigned short* F = gB + (size_t)b * CB * HWD;
    unsigned short* dst = gTB + (size_t)b * CB * HWD;
    const int mrow = t >> 3, cg = t & 7;
    {
        int m = m0 + mrow;
        float d = D[((size_t)0 * NBATCH + b) * NN_ + m]
                + D[((size_t)1 * NBATCH + b) * NN_ + m]
                + D[((size_t)2 * NBATCH + b) * NN_ + m]
                + D[((size_t)3 * NBATCH + b) * NN_ + m];
        float r = 1.0f / d;
        #pragma unroll
        for (int j8 = 0; j8 < 2; j8++) {
            int cbase = cg * 8 + j8 * 64;
            u8s u = *(const u8s*)&F[(size_t)m * CB + cbase];
            #pragma unroll
            for (int e = 0; e < 8; e++)
                T[(cbase + e) * 36 + mrow] = f2bf(bf2f(u[e]) * r);
        }
    }
    __syncthreads();
    const int c = t >> 1, mh = (t & 1) * 16;
    #pragma unroll
    for (int h8 = 0; h8 < 2; h8++)
        *(u8s*)&dst[(size_t)c * HWD + m0 + mh + h8 * 8] =
            *(const u8s*)&T[c * 36 + mh + h8 * 8];
}

// ---------------- k3: y[n][c] = sum_m exp(S[n][m]) * gT[c][m], 32x32x16 -----
// Single __syncthreads per m-iter. Lphi dbuf (stride 132: 264B, 2-way-free
// col-slice reads) + Pl dbuf (stride 68: 136B, 2-way-free).
// Per iter i: gfrag(i) loads | S(i)<-Lphi[i&1] | Lphi[(i+1)&1]<-preg(tile i+1)
// | exp->Pl[i&1] | BARRIER | preg<-tile i+2 | PV(i)<-Pl[i&1],gfrag.
// All loads aged >=500cy at each drain; preg reloaded post-barrier so the
// drain never sees a fresh load.
__global__ __launch_bounds__(256, 3) void k3_attn(
    const unsigned short* __restrict__ thetaB,
    const unsigned short* __restrict__ phiTB,
    const unsigned short* __restrict__ gTB,
    unsigned short* __restrict__ Y)
{
    __shared__ unsigned short Lphi[2][64 * 132];   // [m-local][k], 264B stride
    __shared__ unsigned short Pl[2][64 * 68];      // [n-local][m-local], 136B stride
    const int t = threadIdx.x;
    const int lane = t & 63, w = t >> 6;
    const int l31 = lane & 31, lh = lane >> 5;
    const int qn = w & 1, qm = w >> 1;
    const int rowS = t >> 4, colS = t & 15;
    const int n0 = blockIdx.x * 64, q = blockIdx.y, b = blockIdx.z;
    const unsigned short* th = thetaB + (size_t)b * NN_ * CB;
    const unsigned short* ph = phiTB + (size_t)b * NN_ * CB;
    const unsigned short* gT = gTB + (size_t)b * CB * HWD;

    // persistent theta A-frags: rows n0+qn*32+l31, k = 128 in 8 steps of 16
    v8s ath[8];
    #pragma unroll
    for (int kt = 0; kt < 8; kt++)
        ath[kt] = *(const v8s*)&th[(size_t)(n0 + qn * 32 + l31) * CB + kt * 16 + lh * 8];

    const int mBeg = q * 1024;
    // prologue: stage tile 0 into Lphi[0]; preload preg = tile 1
    v8s preg[4];
    #pragma unroll
    for (int pass = 0; pass < 4; pass++)
        preg[pass] = *(const v8s*)&ph[(size_t)(mBeg + pass * 16 + rowS) * CB + colS * 8];
    #pragma unroll
    for (int pass = 0; pass < 4; pass++)
        *(v8s*)&Lphi[0][(pass * 16 + rowS) * 132 + colS * 8] = preg[pass];
    #pragma unroll
    for (int pass = 0; pass < 4; pass++)
        preg[pass] = *(const v8s*)&ph[(size_t)(mBeg + 64 + pass * 16 + rowS) * CB + colS * 8];
    __syncthreads();

    v16f yacc[2] = {};   // nt = 0,1 (n halves); wave's c-strip = w*32
    #pragma unroll 2
    for (int it = 0; it < 16; ++it) {
        const int cur = it & 1;
        const int m0 = mBeg + it * 64;
        // gT fragments for this iter (consumed in PV, post-barrier)
        v8s gfrag[4];
        #pragma unroll
        for (int ks = 0; ks < 4; ks++)
            gfrag[ks] = *(const v8s*)&gT[(size_t)(w * 32 + l31) * HWD + m0 + ks * 16 + lh * 8];
        // S phase: one 32x32 quadrant per wave, phi from Lphi[cur]
        v16f s = {};
        #pragma unroll
        for (int kt = 0; kt < 8; kt++) {
            v8s bphi = *(const v8s*)&Lphi[cur][(qm * 32 + l31) * 132 + kt * 16 + lh * 8];
            s = MFMA32(ath[kt], bphi, s);
        }
        // stage tile i+1 into the other Lphi buffer (preg loaded last iter,
        // fully landed). Safe: its last readers were S(i-1), pre-barrier(i-1).
        #pragma unroll
        for (int pass = 0; pass < 4; pass++)
            *(v8s*)&Lphi[cur ^ 1][(pass * 16 + rowS) * 132 + colS * 8] = preg[pass];
        // exp + P-write to ping-pong buffer. Safe vs PV(i-2): barrier(i-1).
        #pragma unroll
        for (int reg = 0; reg < 16; reg++) {
            int row = qn * 32 + (reg & 3) + 8 * (reg >> 2) + 4 * lh;   // n-local
            Pl[cur][row * 68 + qm * 32 + l31] = f2bf(__expf(s[reg]));
        }
        __syncthreads();   // the ONLY barrier: Pl[cur]+Lphi[cur^1] visible
        // reload preg with tile i+2 AFTER the barrier so the next drain
        // sees an aged load, not a fresh one.
        const int mP = mBeg + ((it + 2) & 15) * 64;
        #pragma unroll
        for (int pass = 0; pass < 4; pass++)
            preg[pass] = *(const v8s*)&ph[(size_t)(mP + pass * 16 + rowS) * CB + colS * 8];
        // PV phase: wave's 32-c strip (w*32), both n 32-halves
        #pragma unroll
        for (int ks = 0; ks < 4; ks++)
            #pragma unroll
            for (int nt = 0; nt < 2; nt++) {
                v8s ap = *(const v8s*)&Pl[cur][(nt * 32 + l31) * 68 + ks * 16 + lh * 8];
                yacc[nt] = MFMA32(ap, gfrag[ks], yacc[nt]);
            }
    }
    unsigned short* yp = Y + ((size_t)q * NBATCH + b) * CB * HWD;
    #pragma unroll
    for (int nt = 0; nt < 2; nt++)
        #pragma unroll
        for (int reg = 0; reg < 16; reg++) {
            int row = (reg & 3) + 8 * (reg >> 2) + 4 * lh;
            yp[(size_t)(n0 + nt * 32 + row) * CB + w * 32 + l31] = f2bf(yacc[nt][reg]);
        }
}

// ---------------- k4: out = Ww @ (sum Y partials) + Wb + x ------------------
__global__ __launch_bounds__(256, 2) void k4_mfma(
    const float* __restrict__ x, const unsigned short* __restrict__ wwB,
    const float* __restrict__ Wb, const unsigned short* __restrict__ Ybuf,
    float* __restrict__ out)
{
    __shared__ unsigned short Yt[64 * 136];
    const int t = threadIdx.x;
    const int lane = t & 63, w = t >> 6;
    const int ln = lane & 15, quad = lane >> 4;
    const int hw0 = blockIdx.x * 64, o0 = blockIdx.y * 128, b = blockIdx.z;

    const int cb = t >> 1, seg = (t & 1) * 32;
    #pragma unroll
    for (int g8 = 0; g8 < 4; g8++) {
        float sum[8] = {};
        #pragma unroll
        for (int q = 0; q < 4; q++) {
            u8s u = *(const u8s*)&Ybuf[((size_t)q * NBATCH + b) * CB * HWD +
                                       (size_t)cb * HWD + hw0 + seg + g8 * 8];
            #pragma unroll
            for (int j = 0; j < 8; j++) sum[j] += bf2f(u[j]);
        }
        #pragma unroll
        for (int j = 0; j < 8; j++)
            Yt[(seg + g8 * 8 + j) * 136 + cb] = f2bf(sum[j]);
    }
    __syncthreads();

    v8s aw[2][4];
    #pragma unroll
    for (int os = 0; os < 2; os++)
        #pragma unroll
        for (int kt = 0; kt < 4; kt++)
            aw[os][kt] = *(const v8s*)&wwB[(size_t)(o0 + w * 32 + os * 16 + ln) * CB + kt * 32 + quad * 8];

    v4f s[2][4] = {};
    #pragma unroll
    for (int kt = 0; kt < 4; kt++) {
        v8s by[4];
        #pragma unroll
        for (int mt = 0; mt < 4; mt++)
            by[mt] = *(const v8s*)&Yt[(mt * 16 + ln) * 136 + kt * 32 + quad * 8];
        #pragma unroll
        for (int os = 0; os < 2; os++)
            #pragma unroll
            for (int mt = 0; mt < 4; mt++)
                s[os][mt] = MFMA16(aw[os][kt], by[mt], s[os][mt]);
    }
    #pragma unroll
    for (int os = 0; os < 2; os++)
        #pragma unroll
        for (int mt = 0; mt < 4; mt++)
            #pragma unroll
            for (int r = 0; r < 4; r++) {
                int o = o0 + w * 32 + os * 16 + quad * 4 + r;
                size_t idx = (size_t)b * CI * HWD + (size_t)o * HWD + hw0 + mt * 16 + ln;
                out[idx] = s[os][mt][r] + Wb[o] + x[idx];
            }
}

extern "C" void kernel_launch(void* const* d_in, const int* in_sizes, int n_in,
                              void* d_out, int out_size, void* d_ws, size_t ws_size,
                              hipStream_t stream)
{
    const float* x  = (const float*)d_in[0];
    const float* tw = (const float*)d_in[1];
    const float* tb = (const float*)d_in[2];
    const float* pw = (const float*)d_in[3];
    const float* pb = (const float*)d_in[4];
    const float* gw = (const float*)d_in[5];
    const float* gb = (const float*)d_in[6];
    const float* Ww = (const float*)d_in[7];
    const float* Wb = (const float*)d_in[8];
    unsigned short* wsu = (unsigned short*)d_ws;
    float* wsf = (float*)d_ws;
    unsigned short* thetaB = wsu + U_THETA;
    unsigned short* phiTB  = wsu + U_PHIT;
    unsigned short* gB     = wsu + U_G;
    unsigned short* gTB    = wsu + U_GT;
    unsigned short* Ybuf   = wsu + U_Y;
    unsigned short* xTB    = wsu + U_XT;
    unsigned short* wcatB  = wsu + U_WCAT;
    unsigned short* wwB    = wsu + U_WW;
    float* Dbuf = wsf + F_D;
    float* out = (float*)d_out;
    dim3 blk(256, 1, 1);
    hipLaunchKernelGGL(k0_xpose, dim3(64, 5, NBATCH), blk, 0, stream,
                       x, xTB, tw, pw, gw, Ww, wcatB, wwB);
    hipLaunchKernelGGL(k1_mfma, dim3(64, 6, NBATCH), blk, 0, stream,
                       xTB, wcatB, tb, pb, gb, thetaB, phiTB, gB);
    hipLaunchKernelGGL(k2_colsum, dim3(32, 4, NBATCH), blk, 0, stream,
                       thetaB, phiTB, Dbuf);
    hipLaunchKernelGGL(k1b_transpose_scale_g, dim3(128, 1, NBATCH), blk, 0, stream,
                       gB, Dbuf, gTB);
    hipLaunchKernelGGL(k3_attn, dim3(64, 4, NBATCH), blk, 0, stream,
                       thetaB, phiTB, gTB, Ybuf);
    hipLaunchKernelGGL(k4_mfma, dim3(64, 2, NBATCH), blk, 0, stream,
                       x, wwB, Wb, Ybuf, out);
}